// Round 15
// baseline (219.892 us; speedup 1.0000x reference)
//
#include <hip/hip_runtime.h>
#include <hip/hip_bf16.h>
#include <stdint.h>

#define Bn 2
#define Np 50000
#define Cc 81
#define CM1 80
#define KSEL 2048
#define NDET 100
#define NBUCK 2048
#define BUCK_BASE 0x3D000000u
#define BUCK_SHIFT 15
#define SELCAP 4096
#define IMG_W 1333.0f
#define IMG_H 800.0f
#define SCORE_TH 0.05f
#define MIN_SZ 0.01f
#define NMS_TH 0.5f
#define LBLOFF 1401.0f
#define BBOX_CLIP_F 4.135166556742356f
#define CHUNK 32        // proposals per wave (2 rounds of 16)
#define QCAP 320        // LDS queue per wave per round (max 304 used)
#define SEGCAP 640      // global per-wave segment (2 rounds, max 608)
#define BLKX 391        // ceil(Np / (4*CHUNK))
#define WPI  (BLKX*4)   // wave segments per image
#define GXM 64          // mega kernel blocks per image (128 total, co-resident)
#define NBLK (GXM*Bn)

typedef unsigned long long u64;
typedef unsigned int u32;

__device__ __forceinline__ u64 shfl64(u64 v, int src) {
  int lo = __shfl((int)(u32)v, src, 64);
  int hi = __shfl((int)(u32)(v >> 32), src, 64);
  return ((u64)(u32)hi << 32) | (u32)lo;
}

// Software grid barrier (plain-kernel re-implementation of ROCm's gfx9
// grid.sync): release fence + monotonic counter + spin + acquire fence.
// Safe: the mega grid (128 blocks) is always fully co-resident.
__device__ __forceinline__ void gbar(u32* bar, u32 target) {
  __syncthreads();
  __threadfence();
  if (threadIdx.x == 0) {
    atomicAdd(bar, 1u);
    while (atomicAdd(bar, 0u) < target) __builtin_amdgcn_s_sleep(2);
    __threadfence();
  }
  __syncthreads();
}

// Torchvision BoxCoder.decode + clip, non-contracted fp32 to match reference.
__device__ __forceinline__ void decode_box(int row, int c,
    const float* __restrict__ reg, const float* __restrict__ props,
    float& x1, float& y1, float& x2, float& y2) {
  const float4 pr = *reinterpret_cast<const float4*>(props + (size_t)row * 4);
  float w = __fsub_rn(pr.z, pr.x), h = __fsub_rn(pr.w, pr.y);
  float cx = __fadd_rn(pr.x, 0.5f * w), cy = __fadd_rn(pr.y, 0.5f * h);
  const float4 rel = *reinterpret_cast<const float4*>(reg + ((size_t)row * Cc + c) * 4);
  float dx = __fdiv_rn(rel.x, 10.f), dy = __fdiv_rn(rel.y, 10.f);
  float dw = fminf(__fdiv_rn(rel.z, 5.f), BBOX_CLIP_F);
  float dh = fminf(__fdiv_rn(rel.w, 5.f), BBOX_CLIP_F);
  float pcx = __fadd_rn(__fmul_rn(dx, w), cx);
  float pcy = __fadd_rn(__fmul_rn(dy, h), cy);
  float pw = __fmul_rn(expf(dw), w);
  float ph = __fmul_rn(expf(dh), h);
  x1 = fminf(fmaxf(__fsub_rn(pcx, 0.5f * pw), 0.f), IMG_W);
  y1 = fminf(fmaxf(__fsub_rn(pcy, 0.5f * ph), 0.f), IMG_H);
  x2 = fminf(fmaxf(__fadd_rn(pcx, 0.5f * pw), 0.f), IMG_W);
  y2 = fminf(fmaxf(__fadd_rn(pcy, 0.5f * ph), 0.f), IMG_H);
}

// Batched drain (r9/r12-proven): decode+minsize, compact to segment, hist.
__device__ __forceinline__ u32 drain(const u64* Qb, u32 n, int lane, int b,
    const float* __restrict__ reg, const float* __restrict__ props,
    u32* hist, u64* seg, u32 wout) {
  for (u32 qb = 0; qb < n; qb += 64) {
    const bool act = (qb + (u32)lane) < n;
    u64 key = act ? Qb[qb + lane] : 0ull;
    bool valid = false;
    u32 sb = 0;
    if (act) {
      sb = (u32)(key >> 32);
      const u32 idx = ~(u32)key;
      const int pn = (int)(idx / CM1);
      const int c = (int)(idx - (u32)pn * CM1) + 1;
      float x1, y1, x2, y2;
      decode_box(b * Np + pn, c, reg, props, x1, y1, x2, y2);
      valid = (__fsub_rn(x2, x1) >= MIN_SZ) && (__fsub_rn(y2, y1) >= MIN_SZ);
    }
    const u64 bal = __ballot(valid);
    if (valid) {
      seg[wout + (u32)__popcll(bal & ((1ull << lane) - 1ull))] = key;
      u32 bk = (sb - BUCK_BASE) >> BUCK_SHIFT;
      if (bk > (u32)(NBUCK - 1)) bk = NBUCK - 1;
      atomicAdd(&hist[bk], 1u);
    }
    wout += (u32)__popcll(bal);
  }
  return wout;
}

// Pass A (r12-verbatim): direct-register logits loads, 2 rounds of 16
// proposals per wave, prefix-scan emit, drain per round.
__global__ __launch_bounds__(256, 4) void passA_kernel(
    const float* __restrict__ logits, const float* __restrict__ reg,
    const float* __restrict__ props, u64* __restrict__ wseg,
    u32* __restrict__ wcnt, u32* __restrict__ ghist)
{
  __shared__ u64 qbuf[4][QCAP];                        // 10240 B
  __shared__ u32 hist[NBUCK];                          // 8192 B
  const int b = blockIdx.y;
  const int tid = threadIdx.x;
  const int wave = tid >> 6, lane = tid & 63;
  for (int i = tid; i < NBUCK; i += 256) hist[i] = 0;
  __syncthreads();

  const int wslot = (blockIdx.x << 2) + wave;
  u64* Q = qbuf[wave];
  u64* seg = wseg + (size_t)(b * WPI + wslot) * SEGCAP;
  u32 wout = 0;
  const int p = lane >> 2, qd = lane & 3;
  const int cnt_k = (qd == 3) ? 18 : 21;
  #pragma unroll
  for (int r = 0; r < 2; ++r) {
    const int n0 = wslot * CHUNK + r * 16;
    if (n0 >= Np) break;
    const int n_ = n0 + p;
    const float* lrow = logits + ((size_t)b * Np + n_) * Cc + qd * 21;
    float ev[21];
    #pragma unroll
    for (int k = 0; k < 21; ++k)
      ev[k] = (k < cnt_k) ? lrow[k] : -3.4e38f;
    float m = ev[0];
    #pragma unroll
    for (int k = 1; k < 21; ++k) m = fmaxf(m, ev[k]);
    m = fmaxf(m, __shfl_xor(m, 1, 64));
    m = fmaxf(m, __shfl_xor(m, 2, 64));
    float s = 0.f;
    #pragma unroll
    for (int k = 0; k < 21; ++k) {
      ev[k] = (k < cnt_k) ? expf(ev[k] - m) : 0.f;
      s += ev[k];
    }
    s += __shfl_xor(s, 1, 64);
    s += __shfl_xor(s, 2, 64);
    const float thr = SCORE_TH * s;
    u32 emask = 0;
    #pragma unroll
    for (int k = 0; k < 21; ++k) {
      const int c = qd * 21 + k;
      if (c > 0 && ev[k] > thr) emask |= (1u << k);
    }
    const u32 mycnt = __popc(emask);
    u32 inc = mycnt;
    #pragma unroll
    for (int o = 1; o < 64; o <<= 1) {
      const u32 v = (u32)__shfl_up((int)inc, o, 64);
      if (lane >= o) inc += v;
    }
    u32 pos = inc - mycnt;
    const u32 qtot = (u32)__shfl((int)inc, 63, 64);
    u32 em = emask;
    while (em) {
      const int k = (int)__builtin_ctz(em);
      em &= em - 1;
      const int c = qd * 21 + k;
      const u32 sb = __float_as_uint(__fdiv_rn(ev[k], s));
      const u32 idx = (u32)(n_ * CM1 + (c - 1));
      Q[pos++] = ((u64)sb << 32) | (u32)(~idx);
    }
    wout = drain(Q, qtot, lane, b, reg, props, hist, seg, wout);
  }
  if (lane == 0) wcnt[b * WPI + wslot] = wout;
  __syncthreads();
  for (int i = tid; i < NBUCK; i += 256) {
    const u32 v = hist[i];
    if (v) atomicAdd(&ghist[b * NBUCK + i], v);   // fire-and-forget
  }
}

// Mega kernel: thresh -> scatter -> runsort -> tail with software grid
// barriers. 128 blocks x 1024 threads, guaranteed co-resident.
__global__ __launch_bounds__(1024) void mega_kernel(
    const u64* __restrict__ wseg, const u32* __restrict__ wcnt,
    const u32* __restrict__ ghist, u32* __restrict__ gT,
    u32* __restrict__ gTot, u32* __restrict__ boffs, u32* __restrict__ bfill,
    u64* __restrict__ skeys, u64* __restrict__ skeys2,
    const float* __restrict__ reg, const float* __restrict__ props,
    float* __restrict__ out, u32* __restrict__ bar)
{
  __shared__ u64 keys[KSEL];                                     // 16 KB
  __shared__ float obx1[KSEL], oby1[KSEL], obx2[KSEL], oby2[KSEL];
  __shared__ float oar[KSEL], osc[KSEL];                         // 48 KB
  __shared__ unsigned short keptIdx[NDET];
  __shared__ u32 supflags[64];
  __shared__ u32 sh_kc;
  const int b = blockIdx.y;
  const int tid = threadIdx.x;
  const int wave = tid >> 6, lane = tid & 63;

  // ---- phase 1: thresh (wave 0 of block (0,b)); also zeroes bfill ----
  if (blockIdx.x == 0 && wave == 0) {
    const u32* h = ghist + b * NBUCK;
    u32* bo = boffs + b * NBUCK;
    const int SEG = NBUCK / 64;
    u32 segsum = 0;
    for (int t = 0; t < SEG; ++t) segsum += h[lane * SEG + t];
    u32 suf = segsum;
    #pragma unroll
    for (int o = 1; o < 64; o <<= 1) {
      const u32 v = (u32)__shfl_down((int)suf, o, 64);
      if (lane + o < 64) suf += v;
    }
    u32 acc = suf - segsum;
    int myT = -1; u32 totv = 0;
    for (int t = SEG - 1; t >= 0; --t) {
      const int bk = lane * SEG + t;
      bo[bk] = acc;
      bfill[b * NBUCK + bk] = 0u;
      acc += h[bk];
      if (myT < 0 && acc >= (u32)KSEL) { myT = bk; totv = acc; }
    }
    int Tg = myT;
    #pragma unroll
    for (int o = 32; o; o >>= 1) Tg = max(Tg, __shfl_xor(Tg, o, 64));
    if (Tg < 0) {
      if (lane == 0) { gT[b] = 0u; gTot[b] = (acc < (u32)SELCAP) ? acc : (u32)SELCAP; }
    } else if (myT == Tg) {
      gT[b] = (u32)Tg;
      gTot[b] = (totv < (u32)SELCAP) ? totv : (u32)SELCAP;
    }
  }
  gbar(bar, NBLK * 1);

  // ---- phase 2: scatter (wave-per-segment, grid-stride) ----
  {
    const u32 T = gT[b];
    for (u32 sgi = blockIdx.x * 16 + wave; sgi < (u32)WPI; sgi += GXM * 16) {
      const u32 cnt = wcnt[b * WPI + sgi];
      const u64* seg = wseg + (size_t)(b * WPI + sgi) * SEGCAP;
      for (u32 i = lane; i < cnt; i += 64) {
        const u64 key = seg[i];
        const u32 sb = (u32)(key >> 32);
        u32 bk = (sb - BUCK_BASE) >> BUCK_SHIFT;
        if (bk > (u32)(NBUCK - 1)) bk = NBUCK - 1;
        if (bk >= T) {
          const u32 pos = boffs[b * NBUCK + bk] + atomicAdd(&bfill[b * NBUCK + bk], 1u);
          if (pos < (u32)SELCAP) skeys[(size_t)b * SELCAP + pos] = key;
        }
      }
    }
  }
  gbar(bar, NBLK * 2);

  // ---- phase 3: runsort (wave-per-bucket register rank sort, grid-stride) ----
  {
    const u32 T = gT[b];
    const u32 total = gTot[b];
    for (u32 bk = blockIdx.x * 16 + wave; bk < (u32)NBUCK; bk += GXM * 16) {
      if (bk < T) continue;
      const u32 start = boffs[b * NBUCK + bk];
      u32 L = bfill[b * NBUCK + bk];
      if (L == 0 || start >= (u32)KSEL || start >= total) continue;
      if (start + L > total) L = total - start;
      const u64* run = skeys + (size_t)b * SELCAP + start;
      u64* dst = skeys2 + (size_t)b * SELCAP + start;
      if (L <= 128u) {
        const u64 k0 = (lane < (int)L) ? run[lane] : 0ull;
        const u64 k1 = (64 + lane < (int)L) ? run[64 + lane] : 0ull;
        u32 r0 = 0, r1 = 0;
        #pragma unroll
        for (int l = 0; l < 64; ++l) {
          const u64 o0 = shfl64(k0, l);
          const u64 o1 = shfl64(k1, l);
          r0 += (o0 > k0) + (o1 > k0);
          r1 += (o0 > k1) + (o1 > k1);
        }
        if (lane < (int)L) dst[r0] = k0;
        if (64 + lane < (int)L) dst[r1] = k1;
      } else {
        for (u32 i = lane; i < L; i += 64) {
          const u64 k = run[i];
          u32 r = 0;
          for (u32 q = 0; q < L; ++q) r += (run[q] > k);
          dst[r] = k;
        }
      }
    }
  }
  gbar(bar, NBLK * 3);

  // ---- phase 4: tail (r12-verbatim 1024-thread body; block (0,b) only) ----
  if (blockIdx.x != 0) return;
  {
    const u64* sk2 = skeys2 + (size_t)b * SELCAP;
    const u32 totalg = gTot[b];
    const u32 total = (totalg < (u32)KSEL) ? totalg : (u32)KSEL;
    if (tid == 0) sh_kc = 0;

    for (int i = tid; i < KSEL; i += 1024)
      keys[i] = (i < (int)total) ? sk2[i] : 0ull;
    __syncthreads();

    for (int t = tid; t < KSEL; t += 1024) {
      const u64 key = keys[t];
      float x1 = 0, y1 = 0, x2 = 0, y2 = 0, score = 0, lab = 0;
      if (key) {
        const u32 sb = (u32)(key >> 32);
        const u32 idx = ~(u32)key;
        const int n_ = (int)(idx / CM1);
        const int c = (int)(idx % CM1) + 1;
        score = __uint_as_float(sb);
        decode_box(b * Np + n_, c, reg, props, x1, y1, x2, y2);
        lab = (float)c;
      }
      const float offv = __fmul_rn(lab, LBLOFF);
      const float ox1 = __fadd_rn(x1, offv), oy1 = __fadd_rn(y1, offv);
      const float ox2 = __fadd_rn(x2, offv), oy2 = __fadd_rn(y2, offv);
      obx1[t] = ox1; oby1[t] = oy1; obx2[t] = ox2; oby2[t] = oy2;
      oar[t] = __fmul_rn(__fsub_rn(ox2, ox1), __fsub_rn(oy2, oy1));
      osc[t] = score;
    }
    __syncthreads();

    int kc = 0;
    for (int c = 0; c < 32 && kc < NDET; ++c) {
      if (tid < 64) supflags[tid] = 0;
      __syncthreads();
      const int j = (c << 6) + lane;
      const float cx1 = obx1[j], cy1 = oby1[j], cx2 = obx2[j], cy2 = oby2[j], ca = oar[j];
      bool sup = false;
      for (int k = wave; k < kc; k += 16) {
        const int ki = keptIdx[k];
        const float ltx = fmaxf(cx1, obx1[ki]), lty = fmaxf(cy1, oby1[ki]);
        const float rbx = fminf(cx2, obx2[ki]), rby = fminf(cy2, oby2[ki]);
        const float wx = fmaxf(__fsub_rn(rbx, ltx), 0.f);
        const float wy = fmaxf(__fsub_rn(rby, lty), 0.f);
        const float inter = __fmul_rn(wx, wy);
        const float denom = __fadd_rn(__fsub_rn(__fadd_rn(ca, oar[ki]), inter), 1e-9f);
        if (__fdiv_rn(inter, denom) > NMS_TH) sup = true;
      }
      if (sup) supflags[lane] = 1u;   // benign same-value race
      __syncthreads();
      if (wave == 0) {
        u64 rem = __ballot(supflags[lane] != 0u);
        u64 todo = __ballot(osc[j] > 0.f) & ~rem;
        int kcl = kc;
        while (todo && kcl < NDET) {
          const int jb = (int)__builtin_ctzll(todo);
          const int cj = (c << 6) + jb;
          if (lane == 0) keptIdx[kcl] = (unsigned short)cj;
          ++kcl;
          const float kx1 = obx1[cj], ky1 = oby1[cj], kx2 = obx2[cj], ky2 = oby2[cj], ka = oar[cj];
          const float ltx = fmaxf(kx1, cx1), lty = fmaxf(ky1, cy1);
          const float rbx = fminf(kx2, cx2), rby = fminf(ky2, cy2);
          const float wx = fmaxf(__fsub_rn(rbx, ltx), 0.f);
          const float wy = fmaxf(__fsub_rn(rby, lty), 0.f);
          const float inter = __fmul_rn(wx, wy);
          const float denom = __fadd_rn(__fsub_rn(__fadd_rn(ka, ca), inter), 1e-9f);
          const u64 w = __ballot(__fdiv_rn(inter, denom) > NMS_TH);
          rem |= w;
          todo &= ~rem;
          todo &= ~(1ull << jb);
        }
        if (lane == 0) sh_kc = (u32)kcl;
      }
      __syncthreads();
      kc = (int)sh_kc;
    }

    __syncthreads();
    const int kcl = (kc < NDET) ? kc : NDET;
    if (tid < NDET) {
      float bx1 = 0, by1 = 0, bx2 = 0, by2 = 0, sc = 0, lb = -1.f;
      if (tid < kcl) {
        const int i = keptIdx[tid];
        const u64 key = keys[i];
        const u32 idx = ~(u32)key;
        const int n_ = (int)(idx / CM1);
        const int cc = (int)(idx % CM1) + 1;
        decode_box(b * Np + n_, cc, reg, props, bx1, by1, bx2, by2);
        sc = osc[i];
        lb = (float)cc;
      }
      float* ob = out + (size_t)b * NDET * 4;
      ob[tid * 4 + 0] = bx1; ob[tid * 4 + 1] = by1;
      ob[tid * 4 + 2] = bx2; ob[tid * 4 + 3] = by2;
      out[Bn * NDET * 4 + b * NDET + tid] = sc;
      out[Bn * NDET * 4 + Bn * NDET + b * NDET + tid] = lb;
    }
  }
}

extern "C" void kernel_launch(void* const* d_in, const int* in_sizes, int n_in,
                              void* d_out, int out_size, void* d_ws, size_t ws_size,
                              hipStream_t stream) {
  const float* logits = (const float*)d_in[0];
  const float* reg    = (const float*)d_in[1];
  const float* props  = (const float*)d_in[2];
  float* out = (float*)d_out;
  char* ws = (char*)d_ws;

  // Layout: [header(incl. bar) | ghist]  <- memset 0 each call (16 KB + 64 B)
  //         [bfill (zeroed by thresh) | boffs | skeys | skeys2 | wcnt | wseg]
  u32* gT   = (u32*)ws;                        // 2 u32
  u32* gTot = (u32*)(ws + 16);                 // 2 u32
  u32* bar  = (u32*)(ws + 32);                 // 1 u32 (barrier counter)
  size_t off = 64;
  u32* ghist  = (u32*)(ws + off); off += (size_t)Bn * NBUCK * 4;   // 16 KB
  const size_t memset_bytes = off;
  u32* bfill  = (u32*)(ws + off); off += (size_t)Bn * NBUCK * 4;   // 16 KB
  u32* boffs  = (u32*)(ws + off); off += (size_t)Bn * NBUCK * 4;   // 16 KB
  u64* skeys  = (u64*)(ws + off); off += (size_t)Bn * SELCAP * 8;  // 64 KB
  u64* skeys2 = (u64*)(ws + off); off += (size_t)Bn * SELCAP * 8;  // 64 KB
  u32* wcnt   = (u32*)(ws + off); off += (size_t)Bn * WPI * 4;     // 13 KB
  off = (off + 255) & ~(size_t)255;
  u64* wseg   = (u64*)(ws + off); off += (size_t)Bn * WPI * SEGCAP * 8;  // 16 MB
  (void)ws_size;

  hipMemsetAsync(d_ws, 0, memset_bytes, stream);
  passA_kernel<<<dim3(BLKX, Bn), 256, 0, stream>>>(logits, reg, props, wseg, wcnt, ghist);
  mega_kernel<<<dim3(GXM, Bn), 1024, 0, stream>>>(wseg, wcnt, ghist, gT, gTot,
      boffs, bfill, skeys, skeys2, reg, props, out, bar);
}

// Round 16
// 136.046 us; speedup vs baseline: 1.6163x; 1.6163x over previous
//
#include <hip/hip_runtime.h>
#include <hip/hip_bf16.h>
#include <stdint.h>

#define Bn 2
#define Np 50000
#define Cc 81
#define CM1 80
#define KSEL 2048
#define NDET 100
#define NBUCK 2048
#define BUCK_BASE 0x3D000000u
#define BUCK_SHIFT 15
#define SELCAP 4096
#define IMG_W 1333.0f
#define IMG_H 800.0f
#define SCORE_TH 0.05f
#define MIN_SZ 0.01f
#define NMS_TH 0.5f
#define LBLOFF 1401.0f
#define BBOX_CLIP_F 4.135166556742356f
#define CHUNK 32        // proposals per wave (2 rounds of 16)
#define QCAP 320        // LDS queue per wave per round (max 304 used)
#define SEGCAP 640      // global per-wave segment (2 rounds, max 608)
#define BLKX 391        // ceil(Np / (4*CHUNK))
#define WPI  (BLKX*4)   // wave segments per image
#define SSBLK 98        // scatter-sort-tail blocks per image (16 waves each)

typedef unsigned long long u64;
typedef unsigned int u32;

__device__ __forceinline__ u64 shfl64(u64 v, int src) {
  int lo = __shfl((int)(u32)v, src, 64);
  int hi = __shfl((int)(u32)(v >> 32), src, 64);
  return ((u64)(u32)hi << 32) | (u32)lo;
}

// Agent-scope relaxed atomic load/store: bypass the (non-coherent) local
// L1/L2 so within-kernel cross-block data written by atomics is seen fresh.
__device__ __forceinline__ u64 aload64(const u64* p) {
  return __hip_atomic_load(p, __ATOMIC_RELAXED, __HIP_MEMORY_SCOPE_AGENT);
}
__device__ __forceinline__ void astore64(u64* p, u64 v) {
  __hip_atomic_store(p, v, __ATOMIC_RELAXED, __HIP_MEMORY_SCOPE_AGENT);
}
__device__ __forceinline__ u32 aload32(const u32* p) {
  return __hip_atomic_load(p, __ATOMIC_RELAXED, __HIP_MEMORY_SCOPE_AGENT);
}

// Torchvision BoxCoder.decode + clip, non-contracted fp32 to match reference.
__device__ __forceinline__ void decode_box(int row, int c,
    const float* __restrict__ reg, const float* __restrict__ props,
    float& x1, float& y1, float& x2, float& y2) {
  const float4 pr = *reinterpret_cast<const float4*>(props + (size_t)row * 4);
  float w = __fsub_rn(pr.z, pr.x), h = __fsub_rn(pr.w, pr.y);
  float cx = __fadd_rn(pr.x, 0.5f * w), cy = __fadd_rn(pr.y, 0.5f * h);
  const float4 rel = *reinterpret_cast<const float4*>(reg + ((size_t)row * Cc + c) * 4);
  float dx = __fdiv_rn(rel.x, 10.f), dy = __fdiv_rn(rel.y, 10.f);
  float dw = fminf(__fdiv_rn(rel.z, 5.f), BBOX_CLIP_F);
  float dh = fminf(__fdiv_rn(rel.w, 5.f), BBOX_CLIP_F);
  float pcx = __fadd_rn(__fmul_rn(dx, w), cx);
  float pcy = __fadd_rn(__fmul_rn(dy, h), cy);
  float pw = __fmul_rn(expf(dw), w);
  float ph = __fmul_rn(expf(dh), h);
  x1 = fminf(fmaxf(__fsub_rn(pcx, 0.5f * pw), 0.f), IMG_W);
  y1 = fminf(fmaxf(__fsub_rn(pcy, 0.5f * ph), 0.f), IMG_H);
  x2 = fminf(fmaxf(__fadd_rn(pcx, 0.5f * pw), 0.f), IMG_W);
  y2 = fminf(fmaxf(__fadd_rn(pcy, 0.5f * ph), 0.f), IMG_H);
}

// Batched drain (r9/r12-proven): decode+minsize, compact to segment, hist.
__device__ __forceinline__ u32 drain(const u64* Qb, u32 n, int lane, int b,
    const float* __restrict__ reg, const float* __restrict__ props,
    u32* hist, u64* seg, u32 wout) {
  for (u32 qb = 0; qb < n; qb += 64) {
    const bool act = (qb + (u32)lane) < n;
    u64 key = act ? Qb[qb + lane] : 0ull;
    bool valid = false;
    u32 sb = 0;
    if (act) {
      sb = (u32)(key >> 32);
      const u32 idx = ~(u32)key;
      const int pn = (int)(idx / CM1);
      const int c = (int)(idx - (u32)pn * CM1) + 1;
      float x1, y1, x2, y2;
      decode_box(b * Np + pn, c, reg, props, x1, y1, x2, y2);
      valid = (__fsub_rn(x2, x1) >= MIN_SZ) && (__fsub_rn(y2, y1) >= MIN_SZ);
    }
    const u64 bal = __ballot(valid);
    if (valid) {
      seg[wout + (u32)__popcll(bal & ((1ull << lane) - 1ull))] = key;
      u32 bk = (sb - BUCK_BASE) >> BUCK_SHIFT;
      if (bk > (u32)(NBUCK - 1)) bk = NBUCK - 1;
      atomicAdd(&hist[bk], 1u);
    }
    wout += (u32)__popcll(bal);
  }
  return wout;
}

// Pass A (r12-proven) + last-block thresh fold. The __syncthreads after the
// hist flush drains every thread's atomics (compiler emits vmcnt(0) before
// s_barrier); the acq_rel done-counter then gives the last block an ordered
// view; it reads ghist via agent atomic loads (bypass stale local caches).
__global__ __launch_bounds__(256, 4) void passA_kernel(
    const float* __restrict__ logits, const float* __restrict__ reg,
    const float* __restrict__ props, u64* __restrict__ wseg,
    u32* __restrict__ wcnt, u32* __restrict__ ghist, u32* __restrict__ dn0,
    u32* __restrict__ gT, u32* __restrict__ gTot, u32* __restrict__ boffs,
    u32* __restrict__ bfill, u32* __restrict__ wcommit)
{
  __shared__ u64 qbuf[4][QCAP];                        // 10240 B
  __shared__ u32 hist[NBUCK];                          // 8192 B
  __shared__ u32 sh_last;
  const int b = blockIdx.y;
  const int tid = threadIdx.x;
  const int wave = tid >> 6, lane = tid & 63;
  for (int i = tid; i < NBUCK; i += 256) hist[i] = 0;
  __syncthreads();

  const int wslot = (blockIdx.x << 2) + wave;
  u64* Q = qbuf[wave];
  u64* seg = wseg + (size_t)(b * WPI + wslot) * SEGCAP;
  u32 wout = 0;
  const int p = lane >> 2, qd = lane & 3;
  const int cnt_k = (qd == 3) ? 18 : 21;
  #pragma unroll
  for (int r = 0; r < 2; ++r) {
    const int n0 = wslot * CHUNK + r * 16;
    if (n0 >= Np) break;
    const int n_ = n0 + p;
    const float* lrow = logits + ((size_t)b * Np + n_) * Cc + qd * 21;
    float ev[21];
    #pragma unroll
    for (int k = 0; k < 21; ++k)
      ev[k] = (k < cnt_k) ? lrow[k] : -3.4e38f;
    float m = ev[0];
    #pragma unroll
    for (int k = 1; k < 21; ++k) m = fmaxf(m, ev[k]);
    m = fmaxf(m, __shfl_xor(m, 1, 64));
    m = fmaxf(m, __shfl_xor(m, 2, 64));
    float s = 0.f;
    #pragma unroll
    for (int k = 0; k < 21; ++k) {
      ev[k] = (k < cnt_k) ? expf(ev[k] - m) : 0.f;
      s += ev[k];
    }
    s += __shfl_xor(s, 1, 64);
    s += __shfl_xor(s, 2, 64);
    const float thr = SCORE_TH * s;
    u32 emask = 0;
    #pragma unroll
    for (int k = 0; k < 21; ++k) {
      const int c = qd * 21 + k;
      if (c > 0 && ev[k] > thr) emask |= (1u << k);
    }
    const u32 mycnt = __popc(emask);
    u32 inc = mycnt;
    #pragma unroll
    for (int o = 1; o < 64; o <<= 1) {
      const u32 v = (u32)__shfl_up((int)inc, o, 64);
      if (lane >= o) inc += v;
    }
    u32 pos = inc - mycnt;
    const u32 qtot = (u32)__shfl((int)inc, 63, 64);
    u32 em = emask;
    while (em) {
      const int k = (int)__builtin_ctz(em);
      em &= em - 1;
      const int c = qd * 21 + k;
      const u32 sb = __float_as_uint(__fdiv_rn(ev[k], s));
      const u32 idx = (u32)(n_ * CM1 + (c - 1));
      Q[pos++] = ((u64)sb << 32) | (u32)(~idx);
    }
    wout = drain(Q, qtot, lane, b, reg, props, hist, seg, wout);
  }
  if (lane == 0) wcnt[b * WPI + wslot] = wout;
  __syncthreads();
  for (int i = tid; i < NBUCK; i += 256) {
    const u32 v = hist[i];
    if (v) atomicAdd(&ghist[b * NBUCK + i], v);   // memory-side, fire-and-forget
  }
  __syncthreads();   // drains all threads' atomics (vmcnt(0) before barrier)

  // ---- last-block thresh fold ----
  if (tid == 0) {
    const u32 old = __hip_atomic_fetch_add(dn0, 1u, __ATOMIC_ACQ_REL,
                                           __HIP_MEMORY_SCOPE_AGENT);
    sh_last = (old == (u32)(BLKX * Bn - 1)) ? 1u : 0u;
  }
  __syncthreads();
  if (sh_last && wave < Bn) {
    const int bb = wave;   // wave 0 -> image 0, wave 1 -> image 1
    const u32* h = ghist + bb * NBUCK;
    u32* bo = boffs + bb * NBUCK;
    const int SEG = NBUCK / 64;
    u32 hl[SEG];
    u32 segsum = 0;
    for (int t = 0; t < SEG; ++t) {
      hl[t] = aload32(&h[lane * SEG + t]);
      segsum += hl[t];
    }
    u32 suf = segsum;
    #pragma unroll
    for (int o = 1; o < 64; o <<= 1) {
      const u32 v = (u32)__shfl_down((int)suf, o, 64);
      if (lane + o < 64) suf += v;
    }
    u32 acc = suf - segsum;
    int myT = -1; u32 totv = 0;
    for (int t = SEG - 1; t >= 0; --t) {
      const int bk = lane * SEG + t;
      bo[bk] = acc;
      bfill[bb * NBUCK + bk] = 0u;
      wcommit[bb * NBUCK + bk] = 0u;
      acc += hl[t];
      if (myT < 0 && acc >= (u32)KSEL) { myT = bk; totv = acc; }
    }
    int Tg = myT;
    #pragma unroll
    for (int o = 32; o; o >>= 1) Tg = max(Tg, __shfl_xor(Tg, o, 64));
    if (Tg < 0) {
      if (lane == 0) { gT[bb] = 0u; gTot[bb] = (acc < (u32)SELCAP) ? acc : (u32)SELCAP; }
    } else if (myT == Tg) {
      gT[bb] = (u32)Tg;
      gTot[bb] = (totv < (u32)SELCAP) ? totv : (u32)SELCAP;
    }
  }
}

// Scatter + eager per-bucket sort + last-block tail, all in one kernel.
// Placement: position-atomic -> agent key store -> RELEASE commit atomic.
// The unique lane whose commit completes a bucket has an acq_rel-ordered
// view of all its keys; its wave rank-sorts the run immediately.
__global__ __launch_bounds__(1024) void sst_kernel(
    const u64* __restrict__ wseg, const u32* __restrict__ wcnt,
    const u32* __restrict__ ghist, const u32* __restrict__ gT,
    const u32* __restrict__ gTot, const u32* __restrict__ boffs,
    u32* __restrict__ bfill, u32* __restrict__ wcommit,
    u64* __restrict__ skeys, u64* __restrict__ skeys2,
    const float* __restrict__ reg, const float* __restrict__ props,
    float* __restrict__ out, u32* __restrict__ dn1)
{
  __shared__ u64 keys[KSEL];                                     // 16 KB
  __shared__ float obx1[KSEL], oby1[KSEL], obx2[KSEL], oby2[KSEL];
  __shared__ float oar[KSEL], osc[KSEL];                         // 48 KB
  __shared__ unsigned short keptIdx[NDET];
  __shared__ u32 supflags[64];
  __shared__ u32 sh_kc, sh_last;
  const int b = blockIdx.y;
  const int tid = threadIdx.x;
  const int wave = tid >> 6, lane = tid & 63;
  const u32 T = gT[b];

  // ---- phase 1: scatter with eager per-bucket sort ----
  for (u32 sgi = blockIdx.x * 16 + wave; sgi < (u32)WPI; sgi += SSBLK * 16) {
    const u32 cnt = wcnt[b * WPI + sgi];
    const u64* segp = wseg + (size_t)(b * WPI + sgi) * SEGCAP;
    for (u32 i0 = 0; i0 < cnt; i0 += 64) {
      const u32 i = i0 + lane;
      bool completed = false;
      u32 bk_l = 0, st_l = 0, tgt_l = 0;
      if (i < cnt) {
        const u64 key = segp[i];
        const u32 sb = (u32)(key >> 32);
        u32 bk = (sb - BUCK_BASE) >> BUCK_SHIFT;
        if (bk > (u32)(NBUCK - 1)) bk = NBUCK - 1;
        if (bk >= T) {
          const u32 st = boffs[b * NBUCK + bk];
          const u32 tgt = aload32(&ghist[b * NBUCK + bk]);
          const u32 pos = st + atomicAdd(&bfill[b * NBUCK + bk], 1u);
          if (pos < (u32)SELCAP) astore64(&skeys[(size_t)b * SELCAP + pos], key);
          // RELEASE: my key store precedes my commit at the coherence point.
          const u32 oldc = __hip_atomic_fetch_add(&wcommit[b * NBUCK + bk], 1u,
                              __ATOMIC_ACQ_REL, __HIP_MEMORY_SCOPE_AGENT);
          if (oldc + 1 == tgt && st < (u32)SELCAP && st + tgt <= (u32)SELCAP) {
            completed = true; bk_l = bk; st_l = st; tgt_l = tgt;
          }
        }
      }
      u64 cm = __ballot(completed);
      while (cm) {
        const int src = (int)__builtin_ctzll(cm);
        cm &= cm - 1;
        const u32 st = (u32)__shfl((int)st_l, src, 64);
        const u32 L  = (u32)__shfl((int)tgt_l, src, 64);
        const u64* run = skeys + (size_t)b * SELCAP + st;
        u64* dst = skeys2 + (size_t)b * SELCAP + st;
        if (L == 1) {
          if (lane == src) astore64(dst, aload64(run));
        } else if (L <= 128u) {
          const u64 k0 = (lane < (int)L) ? aload64(run + lane) : 0ull;
          const u64 k1 = (64 + lane < (int)L) ? aload64(run + 64 + lane) : 0ull;
          u32 r0 = 0, r1 = 0;
          for (u32 q = 0; q < L; ++q) {
            const u64 kq = (q < 64u) ? shfl64(k0, (int)q) : shfl64(k1, (int)(q - 64));
            r0 += (kq > k0); r1 += (kq > k1);
          }
          if (lane < (int)L) astore64(dst + r0, k0);
          if (64 + lane < (int)L) astore64(dst + r1, k1);
        } else {
          for (u32 ii = lane; ii < L; ii += 64) {
            const u64 k = aload64(run + ii);
            u32 r = 0;
            for (u32 q = 0; q < L; ++q) r += (aload64(run + q) > k);
            astore64(dst + r, k);
          }
        }
      }
    }
  }
  __syncthreads();   // drains this block's stores/atomics

  // ---- last block per image runs the tail ----
  if (tid == 0) {
    const u32 old = __hip_atomic_fetch_add(&dn1[b], 1u, __ATOMIC_ACQ_REL,
                                           __HIP_MEMORY_SCOPE_AGENT);
    sh_last = (old == (u32)(SSBLK - 1)) ? 1u : 0u;
  }
  __syncthreads();
  if (!sh_last) return;

  // ---- tail (r12-verbatim 1024-thread body; skeys2 via agent loads) ----
  {
    const u64* sk2 = skeys2 + (size_t)b * SELCAP;
    const u32 totalg = gTot[b];
    const u32 total = (totalg < (u32)KSEL) ? totalg : (u32)KSEL;
    if (tid == 0) sh_kc = 0;

    for (int i = tid; i < KSEL; i += 1024)
      keys[i] = (i < (int)total) ? aload64(&sk2[i]) : 0ull;
    __syncthreads();

    for (int t = tid; t < KSEL; t += 1024) {
      const u64 key = keys[t];
      float x1 = 0, y1 = 0, x2 = 0, y2 = 0, score = 0, lab = 0;
      if (key) {
        const u32 sb = (u32)(key >> 32);
        const u32 idx = ~(u32)key;
        const int n_ = (int)(idx / CM1);
        const int c = (int)(idx % CM1) + 1;
        score = __uint_as_float(sb);
        decode_box(b * Np + n_, c, reg, props, x1, y1, x2, y2);
        lab = (float)c;
      }
      const float offv = __fmul_rn(lab, LBLOFF);
      const float ox1 = __fadd_rn(x1, offv), oy1 = __fadd_rn(y1, offv);
      const float ox2 = __fadd_rn(x2, offv), oy2 = __fadd_rn(y2, offv);
      obx1[t] = ox1; oby1[t] = oy1; obx2[t] = ox2; oby2[t] = oy2;
      oar[t] = __fmul_rn(__fsub_rn(ox2, ox1), __fsub_rn(oy2, oy1));
      osc[t] = score;
    }
    __syncthreads();

    int kc = 0;
    for (int c = 0; c < 32 && kc < NDET; ++c) {
      if (tid < 64) supflags[tid] = 0;
      __syncthreads();
      const int j = (c << 6) + lane;
      const float cx1 = obx1[j], cy1 = oby1[j], cx2 = obx2[j], cy2 = oby2[j], ca = oar[j];
      bool sup = false;
      for (int k = wave; k < kc; k += 16) {
        const int ki = keptIdx[k];
        const float ltx = fmaxf(cx1, obx1[ki]), lty = fmaxf(cy1, oby1[ki]);
        const float rbx = fminf(cx2, obx2[ki]), rby = fminf(cy2, oby2[ki]);
        const float wx = fmaxf(__fsub_rn(rbx, ltx), 0.f);
        const float wy = fmaxf(__fsub_rn(rby, lty), 0.f);
        const float inter = __fmul_rn(wx, wy);
        const float denom = __fadd_rn(__fsub_rn(__fadd_rn(ca, oar[ki]), inter), 1e-9f);
        if (__fdiv_rn(inter, denom) > NMS_TH) sup = true;
      }
      if (sup) supflags[lane] = 1u;   // benign same-value race
      __syncthreads();
      if (wave == 0) {
        u64 rem = __ballot(supflags[lane] != 0u);
        u64 todo = __ballot(osc[j] > 0.f) & ~rem;
        int kcl = kc;
        while (todo && kcl < NDET) {
          const int jb = (int)__builtin_ctzll(todo);
          const int cj = (c << 6) + jb;
          if (lane == 0) keptIdx[kcl] = (unsigned short)cj;
          ++kcl;
          const float kx1 = obx1[cj], ky1 = oby1[cj], kx2 = obx2[cj], ky2 = oby2[cj], ka = oar[cj];
          const float ltx = fmaxf(kx1, cx1), lty = fmaxf(ky1, cy1);
          const float rbx = fminf(kx2, cx2), rby = fminf(ky2, cy2);
          const float wx = fmaxf(__fsub_rn(rbx, ltx), 0.f);
          const float wy = fmaxf(__fsub_rn(rby, lty), 0.f);
          const float inter = __fmul_rn(wx, wy);
          const float denom = __fadd_rn(__fsub_rn(__fadd_rn(ka, ca), inter), 1e-9f);
          const u64 w = __ballot(__fdiv_rn(inter, denom) > NMS_TH);
          rem |= w;
          todo &= ~rem;
          todo &= ~(1ull << jb);
        }
        if (lane == 0) sh_kc = (u32)kcl;
      }
      __syncthreads();
      kc = (int)sh_kc;
    }

    __syncthreads();
    const int kcl = (kc < NDET) ? kc : NDET;
    if (tid < NDET) {
      float bx1 = 0, by1 = 0, bx2 = 0, by2 = 0, sc = 0, lb = -1.f;
      if (tid < kcl) {
        const int i = keptIdx[tid];
        const u64 key = keys[i];
        const u32 idx = ~(u32)key;
        const int n_ = (int)(idx / CM1);
        const int cc = (int)(idx % CM1) + 1;
        decode_box(b * Np + n_, cc, reg, props, bx1, by1, bx2, by2);
        sc = osc[i];
        lb = (float)cc;
      }
      float* ob = out + (size_t)b * NDET * 4;
      ob[tid * 4 + 0] = bx1; ob[tid * 4 + 1] = by1;
      ob[tid * 4 + 2] = bx2; ob[tid * 4 + 3] = by2;
      out[Bn * NDET * 4 + b * NDET + tid] = sc;
      out[Bn * NDET * 4 + Bn * NDET + b * NDET + tid] = lb;
    }
  }
}

extern "C" void kernel_launch(void* const* d_in, const int* in_sizes, int n_in,
                              void* d_out, int out_size, void* d_ws, size_t ws_size,
                              hipStream_t stream) {
  const float* logits = (const float*)d_in[0];
  const float* reg    = (const float*)d_in[1];
  const float* props  = (const float*)d_in[2];
  float* out = (float*)d_out;
  char* ws = (char*)d_ws;

  // Layout: [header | ghist]  <- memset 0 each call (16 KB + 64 B)
  //         [bfill/wcommit (zeroed by thresh) | boffs | skeys | skeys2 | wcnt | wseg]
  u32* gT   = (u32*)ws;                        // 2 u32
  u32* gTot = (u32*)(ws + 16);                 // 2 u32
  u32* dn0  = (u32*)(ws + 32);                 // 1 u32
  u32* dn1  = (u32*)(ws + 40);                 // 2 u32
  size_t off = 64;
  u32* ghist   = (u32*)(ws + off); off += (size_t)Bn * NBUCK * 4;   // 16 KB
  const size_t memset_bytes = off;
  u32* bfill   = (u32*)(ws + off); off += (size_t)Bn * NBUCK * 4;   // 16 KB
  u32* wcommit = (u32*)(ws + off); off += (size_t)Bn * NBUCK * 4;   // 16 KB
  u32* boffs   = (u32*)(ws + off); off += (size_t)Bn * NBUCK * 4;   // 16 KB
  u64* skeys   = (u64*)(ws + off); off += (size_t)Bn * SELCAP * 8;  // 64 KB
  u64* skeys2  = (u64*)(ws + off); off += (size_t)Bn * SELCAP * 8;  // 64 KB
  u32* wcnt    = (u32*)(ws + off); off += (size_t)Bn * WPI * 4;     // 13 KB
  off = (off + 255) & ~(size_t)255;
  u64* wseg    = (u64*)(ws + off); off += (size_t)Bn * WPI * SEGCAP * 8;  // 16 MB
  (void)ws_size;

  hipMemsetAsync(d_ws, 0, memset_bytes, stream);
  passA_kernel<<<dim3(BLKX, Bn), 256, 0, stream>>>(logits, reg, props, wseg,
      wcnt, ghist, dn0, gT, gTot, boffs, bfill, wcommit);
  sst_kernel<<<dim3(SSBLK, Bn), 1024, 0, stream>>>(wseg, wcnt, ghist, gT, gTot,
      boffs, bfill, wcommit, skeys, skeys2, reg, props, out, dn1);
}

// Round 17
// 90.704 us; speedup vs baseline: 2.4243x; 1.4999x over previous
//
#include <hip/hip_runtime.h>
#include <hip/hip_bf16.h>
#include <stdint.h>

#define Bn 2
#define Np 50000
#define Cc 81
#define CM1 80
#define KSEL 2048
#define NDET 100
#define NBUCK 2048
#define BUCK_BASE 0x3D000000u
#define BUCK_SHIFT 15
#define SELCAP 4096
#define IMG_W 1333.0f
#define IMG_H 800.0f
#define SCORE_TH 0.05f
#define MIN_SZ 0.01f
#define NMS_TH 0.5f
#define LBLOFF 1401.0f
#define BBOX_CLIP_F 4.135166556742356f
#define CHUNK 32        // proposals per wave (2 rounds of 16)
#define QCAP 320        // LDS queue per wave per round (max 304 used)
#define SEGCAP 640      // global per-wave segment (2 rounds, max 608)
#define BLKX 391        // ceil(Np / (4*CHUNK))
#define WPI  (BLKX*4)   // wave segments per image
#define RS_WPB 4        // runsort waves per block

typedef unsigned long long u64;
typedef unsigned int u32;

__device__ __forceinline__ u64 shfl64(u64 v, int src) {
  int lo = __shfl((int)(u32)v, src, 64);
  int hi = __shfl((int)(u32)(v >> 32), src, 64);
  return ((u64)(u32)hi << 32) | (u32)lo;
}

__device__ __forceinline__ u32 aload32(const u32* p) {
  return __hip_atomic_load(p, __ATOMIC_RELAXED, __HIP_MEMORY_SCOPE_AGENT);
}

// Torchvision BoxCoder.decode + clip, non-contracted fp32 to match reference.
__device__ __forceinline__ void decode_box(int row, int c,
    const float* __restrict__ reg, const float* __restrict__ props,
    float& x1, float& y1, float& x2, float& y2) {
  const float4 pr = *reinterpret_cast<const float4*>(props + (size_t)row * 4);
  float w = __fsub_rn(pr.z, pr.x), h = __fsub_rn(pr.w, pr.y);
  float cx = __fadd_rn(pr.x, 0.5f * w), cy = __fadd_rn(pr.y, 0.5f * h);
  const float4 rel = *reinterpret_cast<const float4*>(reg + ((size_t)row * Cc + c) * 4);
  float dx = __fdiv_rn(rel.x, 10.f), dy = __fdiv_rn(rel.y, 10.f);
  float dw = fminf(__fdiv_rn(rel.z, 5.f), BBOX_CLIP_F);
  float dh = fminf(__fdiv_rn(rel.w, 5.f), BBOX_CLIP_F);
  float pcx = __fadd_rn(__fmul_rn(dx, w), cx);
  float pcy = __fadd_rn(__fmul_rn(dy, h), cy);
  float pw = __fmul_rn(expf(dw), w);
  float ph = __fmul_rn(expf(dh), h);
  x1 = fminf(fmaxf(__fsub_rn(pcx, 0.5f * pw), 0.f), IMG_W);
  y1 = fminf(fmaxf(__fsub_rn(pcy, 0.5f * ph), 0.f), IMG_H);
  x2 = fminf(fmaxf(__fadd_rn(pcx, 0.5f * pw), 0.f), IMG_W);
  y2 = fminf(fmaxf(__fadd_rn(pcy, 0.5f * ph), 0.f), IMG_H);
}

// Batched drain (r9/r12-proven): decode+minsize, compact to segment, hist.
__device__ __forceinline__ u32 drain(const u64* Qb, u32 n, int lane, int b,
    const float* __restrict__ reg, const float* __restrict__ props,
    u32* hist, u64* seg, u32 wout) {
  for (u32 qb = 0; qb < n; qb += 64) {
    const bool act = (qb + (u32)lane) < n;
    u64 key = act ? Qb[qb + lane] : 0ull;
    bool valid = false;
    u32 sb = 0;
    if (act) {
      sb = (u32)(key >> 32);
      const u32 idx = ~(u32)key;
      const int pn = (int)(idx / CM1);
      const int c = (int)(idx - (u32)pn * CM1) + 1;
      float x1, y1, x2, y2;
      decode_box(b * Np + pn, c, reg, props, x1, y1, x2, y2);
      valid = (__fsub_rn(x2, x1) >= MIN_SZ) && (__fsub_rn(y2, y1) >= MIN_SZ);
    }
    const u64 bal = __ballot(valid);
    if (valid) {
      seg[wout + (u32)__popcll(bal & ((1ull << lane) - 1ull))] = key;
      u32 bk = (sb - BUCK_BASE) >> BUCK_SHIFT;
      if (bk > (u32)(NBUCK - 1)) bk = NBUCK - 1;
      atomicAdd(&hist[bk], 1u);
    }
    wout += (u32)__popcll(bal);
  }
  return wout;
}

// Pass A (r12-proven) + last-block thresh fold (r16-proven): the final
// block (done-counter, acq_rel) reads ghist via agent atomic loads and
// computes T / suffix offsets / totals, zeroing bfill along the way.
__global__ __launch_bounds__(256, 4) void passA_kernel(
    const float* __restrict__ logits, const float* __restrict__ reg,
    const float* __restrict__ props, u64* __restrict__ wseg,
    u32* __restrict__ wcnt, u32* __restrict__ ghist, u32* __restrict__ dn0,
    u32* __restrict__ gT, u32* __restrict__ gTot, u32* __restrict__ boffs,
    u32* __restrict__ bfill)
{
  __shared__ u64 qbuf[4][QCAP];                        // 10240 B
  __shared__ u32 hist[NBUCK];                          // 8192 B
  __shared__ u32 sh_last;
  const int b = blockIdx.y;
  const int tid = threadIdx.x;
  const int wave = tid >> 6, lane = tid & 63;
  for (int i = tid; i < NBUCK; i += 256) hist[i] = 0;
  __syncthreads();

  const int wslot = (blockIdx.x << 2) + wave;
  u64* Q = qbuf[wave];
  u64* seg = wseg + (size_t)(b * WPI + wslot) * SEGCAP;
  u32 wout = 0;
  const int p = lane >> 2, qd = lane & 3;
  const int cnt_k = (qd == 3) ? 18 : 21;
  #pragma unroll
  for (int r = 0; r < 2; ++r) {
    const int n0 = wslot * CHUNK + r * 16;
    if (n0 >= Np) break;
    const int n_ = n0 + p;
    const float* lrow = logits + ((size_t)b * Np + n_) * Cc + qd * 21;
    float ev[21];
    #pragma unroll
    for (int k = 0; k < 21; ++k)
      ev[k] = (k < cnt_k) ? lrow[k] : -3.4e38f;
    float m = ev[0];
    #pragma unroll
    for (int k = 1; k < 21; ++k) m = fmaxf(m, ev[k]);
    m = fmaxf(m, __shfl_xor(m, 1, 64));
    m = fmaxf(m, __shfl_xor(m, 2, 64));
    float s = 0.f;
    #pragma unroll
    for (int k = 0; k < 21; ++k) {
      ev[k] = (k < cnt_k) ? expf(ev[k] - m) : 0.f;
      s += ev[k];
    }
    s += __shfl_xor(s, 1, 64);
    s += __shfl_xor(s, 2, 64);
    const float thr = SCORE_TH * s;
    u32 emask = 0;
    #pragma unroll
    for (int k = 0; k < 21; ++k) {
      const int c = qd * 21 + k;
      if (c > 0 && ev[k] > thr) emask |= (1u << k);
    }
    const u32 mycnt = __popc(emask);
    u32 inc = mycnt;
    #pragma unroll
    for (int o = 1; o < 64; o <<= 1) {
      const u32 v = (u32)__shfl_up((int)inc, o, 64);
      if (lane >= o) inc += v;
    }
    u32 pos = inc - mycnt;
    const u32 qtot = (u32)__shfl((int)inc, 63, 64);
    u32 em = emask;
    while (em) {
      const int k = (int)__builtin_ctz(em);
      em &= em - 1;
      const int c = qd * 21 + k;
      const u32 sb = __float_as_uint(__fdiv_rn(ev[k], s));
      const u32 idx = (u32)(n_ * CM1 + (c - 1));
      Q[pos++] = ((u64)sb << 32) | (u32)(~idx);
    }
    wout = drain(Q, qtot, lane, b, reg, props, hist, seg, wout);
  }
  if (lane == 0) wcnt[b * WPI + wslot] = wout;
  __syncthreads();
  for (int i = tid; i < NBUCK; i += 256) {
    const u32 v = hist[i];
    if (v) atomicAdd(&ghist[b * NBUCK + i], v);   // memory-side, fire-and-forget
  }
  __syncthreads();   // drains all threads' atomics (vmcnt(0) before barrier)

  // ---- last-block thresh fold (r16-proven) ----
  if (tid == 0) {
    const u32 old = __hip_atomic_fetch_add(dn0, 1u, __ATOMIC_ACQ_REL,
                                           __HIP_MEMORY_SCOPE_AGENT);
    sh_last = (old == (u32)(BLKX * Bn - 1)) ? 1u : 0u;
  }
  __syncthreads();
  if (sh_last && wave < Bn) {
    const int bb = wave;   // wave 0 -> image 0, wave 1 -> image 1
    const u32* h = ghist + bb * NBUCK;
    u32* bo = boffs + bb * NBUCK;
    const int SEG = NBUCK / 64;
    u32 hl[SEG];
    u32 segsum = 0;
    #pragma unroll
    for (int t = 0; t < SEG; ++t) {
      hl[t] = aload32(&h[lane * SEG + t]);
      segsum += hl[t];
    }
    u32 suf = segsum;
    #pragma unroll
    for (int o = 1; o < 64; o <<= 1) {
      const u32 v = (u32)__shfl_down((int)suf, o, 64);
      if (lane + o < 64) suf += v;
    }
    u32 acc = suf - segsum;
    int myT = -1; u32 totv = 0;
    #pragma unroll
    for (int t = SEG - 1; t >= 0; --t) {
      const int bk = lane * SEG + t;
      bo[bk] = acc;
      bfill[bb * NBUCK + bk] = 0u;
      acc += hl[t];
      if (myT < 0 && acc >= (u32)KSEL) { myT = bk; totv = acc; }
    }
    int Tg = myT;
    #pragma unroll
    for (int o = 32; o; o >>= 1) Tg = max(Tg, __shfl_xor(Tg, o, 64));
    if (Tg < 0) {
      if (lane == 0) { gT[bb] = 0u; gTot[bb] = (acc < (u32)SELCAP) ? acc : (u32)SELCAP; }
    } else if (myT == Tg) {
      gT[bb] = (u32)Tg;
      gTot[bb] = (totv < (u32)SELCAP) ? totv : (u32)SELCAP;
    }
  }
}

// Scatter (r12-verbatim): wave-per-segment, per-bucket fill atomics.
__global__ __launch_bounds__(256) void scatter_kernel(
    const u64* __restrict__ wseg, const u32* __restrict__ wcnt,
    const u32* __restrict__ gT, const u32* __restrict__ boffs,
    u32* __restrict__ bfill, u64* __restrict__ skeys)
{
  const int b = blockIdx.y;
  const u32 T = gT[b];
  const int wave = threadIdx.x >> 6, lane = threadIdx.x & 63;
  const u32 sgi = blockIdx.x * 4 + wave;
  if (sgi >= (u32)WPI) return;
  const u32 cnt = wcnt[b * WPI + sgi];
  const u64* seg = wseg + (size_t)(b * WPI + sgi) * SEGCAP;
  for (u32 i = lane; i < cnt; i += 64) {
    const u64 key = seg[i];
    const u32 sb = (u32)(key >> 32);
    u32 bk = (sb - BUCK_BASE) >> BUCK_SHIFT;
    if (bk > (u32)(NBUCK - 1)) bk = NBUCK - 1;
    if (bk >= T) {
      const u32 pos = boffs[b * NBUCK + bk] + atomicAdd(&bfill[b * NBUCK + bk], 1u);
      if (pos < (u32)SELCAP) skeys[(size_t)b * SELCAP + pos] = key;
    }
  }
}

// Runsort (r12-verbatim): wave-per-bucket register rank sort, src->dst.
__global__ __launch_bounds__(256) void runsort_kernel(
    const u64* __restrict__ skeys, u64* __restrict__ skeys2,
    const u32* __restrict__ gT, const u32* __restrict__ gTot,
    const u32* __restrict__ boffs, const u32* __restrict__ bfill)
{
  const int b = blockIdx.y;
  const int wave = threadIdx.x >> 6, lane = threadIdx.x & 63;
  const u32 bk = blockIdx.x * RS_WPB + wave;
  if (bk >= (u32)NBUCK || bk < gT[b]) return;
  const u32 total = gTot[b];
  const u32 start = boffs[b * NBUCK + bk];
  u32 L = bfill[b * NBUCK + bk];
  if (L == 0 || start >= (u32)KSEL || start >= total) return;
  if (start + L > total) L = total - start;
  const u64* run = skeys + (size_t)b * SELCAP + start;
  u64* dst = skeys2 + (size_t)b * SELCAP + start;
  if (L <= 128u) {
    const u64 k0 = (lane < (int)L) ? run[lane] : 0ull;
    const u64 k1 = (64 + lane < (int)L) ? run[64 + lane] : 0ull;
    u32 r0 = 0, r1 = 0;
    #pragma unroll
    for (int l = 0; l < 64; ++l) {
      const u64 o0 = shfl64(k0, l);
      const u64 o1 = shfl64(k1, l);
      r0 += (o0 > k0) + (o1 > k0);
      r1 += (o0 > k1) + (o1 > k1);
    }
    if (lane < (int)L) dst[r0] = k0;
    if (64 + lane < (int)L) dst[r1] = k1;
  } else {
    for (u32 i = lane; i < L; i += 64) {
      const u64 k = run[i];
      u32 r = 0;
      for (u32 q = 0; q < L; ++q) r += (run[q] > k);
      dst[r] = k;
    }
  }
}

// Tail (r12-verbatim): decode top-2048 to LDS SoA, greedy NMS (16-wave
// phase1 + wave-0 resolve), early-exit at 100, write outputs.
__global__ __launch_bounds__(1024) void tail_kernel(
    const u64* __restrict__ skeys2, const u32* __restrict__ gTot,
    const float* __restrict__ reg, const float* __restrict__ props,
    float* __restrict__ out)
{
  __shared__ u64 keys[KSEL];                                     // 16 KB
  __shared__ float obx1[KSEL], oby1[KSEL], obx2[KSEL], oby2[KSEL];
  __shared__ float oar[KSEL], osc[KSEL];                         // 48 KB
  __shared__ unsigned short keptIdx[NDET];
  __shared__ u32 supflags[64];
  __shared__ u32 sh_kc;
  const int b = blockIdx.x;
  const int tid = threadIdx.x;
  const int wave = tid >> 6, lane = tid & 63;
  const u32 total = gTot[b];
  if (tid == 0) sh_kc = 0;

  for (int i = tid; i < KSEL; i += 1024)
    keys[i] = (i < (int)total) ? skeys2[(size_t)b * SELCAP + i] : 0ull;
  __syncthreads();

  for (int t = tid; t < KSEL; t += 1024) {
    const u64 key = keys[t];
    float x1 = 0, y1 = 0, x2 = 0, y2 = 0, score = 0, lab = 0;
    if (key) {
      const u32 sb = (u32)(key >> 32);
      const u32 idx = ~(u32)key;
      const int n_ = (int)(idx / CM1);
      const int c = (int)(idx % CM1) + 1;
      score = __uint_as_float(sb);
      decode_box(b * Np + n_, c, reg, props, x1, y1, x2, y2);
      lab = (float)c;
    }
    const float offv = __fmul_rn(lab, LBLOFF);
    const float ox1 = __fadd_rn(x1, offv), oy1 = __fadd_rn(y1, offv);
    const float ox2 = __fadd_rn(x2, offv), oy2 = __fadd_rn(y2, offv);
    obx1[t] = ox1; oby1[t] = oy1; obx2[t] = ox2; oby2[t] = oy2;
    oar[t] = __fmul_rn(__fsub_rn(ox2, ox1), __fsub_rn(oy2, oy1));
    osc[t] = score;
  }
  __syncthreads();

  int kc = 0;
  for (int c = 0; c < 32 && kc < NDET; ++c) {
    if (tid < 64) supflags[tid] = 0;
    __syncthreads();
    const int j = (c << 6) + lane;
    const float cx1 = obx1[j], cy1 = oby1[j], cx2 = obx2[j], cy2 = oby2[j], ca = oar[j];
    bool sup = false;
    for (int k = wave; k < kc; k += 16) {
      const int ki = keptIdx[k];
      const float ltx = fmaxf(cx1, obx1[ki]), lty = fmaxf(cy1, oby1[ki]);
      const float rbx = fminf(cx2, obx2[ki]), rby = fminf(cy2, oby2[ki]);
      const float wx = fmaxf(__fsub_rn(rbx, ltx), 0.f);
      const float wy = fmaxf(__fsub_rn(rby, lty), 0.f);
      const float inter = __fmul_rn(wx, wy);
      const float denom = __fadd_rn(__fsub_rn(__fadd_rn(ca, oar[ki]), inter), 1e-9f);
      if (__fdiv_rn(inter, denom) > NMS_TH) sup = true;
    }
    if (sup) supflags[lane] = 1u;   // benign same-value race
    __syncthreads();
    if (wave == 0) {
      u64 rem = __ballot(supflags[lane] != 0u);
      u64 todo = __ballot(osc[j] > 0.f) & ~rem;
      int kcl = kc;
      while (todo && kcl < NDET) {
        const int jb = (int)__builtin_ctzll(todo);
        const int cj = (c << 6) + jb;
        if (lane == 0) keptIdx[kcl] = (unsigned short)cj;
        ++kcl;
        const float kx1 = obx1[cj], ky1 = oby1[cj], kx2 = obx2[cj], ky2 = oby2[cj], ka = oar[cj];
        const float ltx = fmaxf(kx1, cx1), lty = fmaxf(ky1, cy1);
        const float rbx = fminf(kx2, cx2), rby = fminf(ky2, cy2);
        const float wx = fmaxf(__fsub_rn(rbx, ltx), 0.f);
        const float wy = fmaxf(__fsub_rn(rby, lty), 0.f);
        const float inter = __fmul_rn(wx, wy);
        const float denom = __fadd_rn(__fsub_rn(__fadd_rn(ka, ca), inter), 1e-9f);
        const u64 w = __ballot(__fdiv_rn(inter, denom) > NMS_TH);
        rem |= w;
        todo &= ~rem;
        todo &= ~(1ull << jb);
      }
      if (lane == 0) sh_kc = (u32)kcl;
    }
    __syncthreads();
    kc = (int)sh_kc;
  }

  __syncthreads();
  const int kcl = (kc < NDET) ? kc : NDET;
  if (tid < NDET) {
    float bx1 = 0, by1 = 0, bx2 = 0, by2 = 0, sc = 0, lb = -1.f;
    if (tid < kcl) {
      const int i = keptIdx[tid];
      const u64 key = keys[i];
      const u32 idx = ~(u32)key;
      const int n_ = (int)(idx / CM1);
      const int cc = (int)(idx % CM1) + 1;
      decode_box(b * Np + n_, cc, reg, props, bx1, by1, bx2, by2);
      sc = osc[i];
      lb = (float)cc;
    }
    float* ob = out + (size_t)b * NDET * 4;
    ob[tid * 4 + 0] = bx1; ob[tid * 4 + 1] = by1;
    ob[tid * 4 + 2] = bx2; ob[tid * 4 + 3] = by2;
    out[Bn * NDET * 4 + b * NDET + tid] = sc;
    out[Bn * NDET * 4 + Bn * NDET + b * NDET + tid] = lb;
  }
}

extern "C" void kernel_launch(void* const* d_in, const int* in_sizes, int n_in,
                              void* d_out, int out_size, void* d_ws, size_t ws_size,
                              hipStream_t stream) {
  const float* logits = (const float*)d_in[0];
  const float* reg    = (const float*)d_in[1];
  const float* props  = (const float*)d_in[2];
  float* out = (float*)d_out;
  char* ws = (char*)d_ws;

  // Layout: [header(dn0) | ghist]  <- memset 0 each call (16 KB + 64 B)
  //         [bfill (zeroed in fold) | boffs | skeys | skeys2 | wcnt | wseg]
  u32* gT   = (u32*)ws;                        // 2 u32
  u32* gTot = (u32*)(ws + 16);                 // 2 u32
  u32* dn0  = (u32*)(ws + 32);                 // 1 u32
  size_t off = 64;
  u32* ghist  = (u32*)(ws + off); off += (size_t)Bn * NBUCK * 4;   // 16 KB
  const size_t memset_bytes = off;
  u32* bfill  = (u32*)(ws + off); off += (size_t)Bn * NBUCK * 4;   // 16 KB
  u32* boffs  = (u32*)(ws + off); off += (size_t)Bn * NBUCK * 4;   // 16 KB
  u64* skeys  = (u64*)(ws + off); off += (size_t)Bn * SELCAP * 8;  // 64 KB
  u64* skeys2 = (u64*)(ws + off); off += (size_t)Bn * SELCAP * 8;  // 64 KB
  u32* wcnt   = (u32*)(ws + off); off += (size_t)Bn * WPI * 4;     // 13 KB
  off = (off + 255) & ~(size_t)255;
  u64* wseg   = (u64*)(ws + off); off += (size_t)Bn * WPI * SEGCAP * 8;  // 16 MB
  (void)ws_size;

  hipMemsetAsync(d_ws, 0, memset_bytes, stream);
  passA_kernel<<<dim3(BLKX, Bn), 256, 0, stream>>>(logits, reg, props, wseg,
      wcnt, ghist, dn0, gT, gTot, boffs, bfill);
  scatter_kernel<<<dim3((WPI + 3) / 4, Bn), 256, 0, stream>>>(wseg, wcnt, gT, boffs, bfill, skeys);
  runsort_kernel<<<dim3(NBUCK / RS_WPB, Bn), 256, 0, stream>>>(skeys, skeys2, gT, gTot, boffs, bfill);
  tail_kernel<<<dim3(Bn), 1024, 0, stream>>>(skeys2, gTot, reg, props, out);
}

// Round 18
// 77.886 us; speedup vs baseline: 2.8232x; 1.1646x over previous
//
#include <hip/hip_runtime.h>
#include <hip/hip_bf16.h>
#include <stdint.h>

#define Bn 2
#define Np 50000
#define Cc 81
#define CM1 80
#define KSEL 2048
#define NDET 100
#define NBUCK 2048
#define BUCK_BASE 0x3D000000u
#define BUCK_SHIFT 15
#define SELCAP 4096
#define IMG_W 1333.0f
#define IMG_H 800.0f
#define SCORE_TH 0.05f
#define MIN_SZ 0.01f
#define NMS_TH 0.5f
#define LBLOFF 1401.0f
#define BBOX_CLIP_F 4.135166556742356f
#define CHUNK 32       // proposals per wave (2 rounds of 16)
#define QCAP 320       // LDS queue per wave per round (max 304 used)
#define SEGCAP 640     // global per-wave segment (2 rounds, max 608)
#define BLKX 391       // ceil(Np / (4*CHUNK))
#define WPI  (BLKX*4)  // wave segments per image
#define RS_WPB 4       // runsort waves per block

typedef unsigned long long u64;
typedef unsigned int u32;

__device__ __forceinline__ u64 shfl64(u64 v, int src) {
  int lo = __shfl((int)(u32)v, src, 64);
  int hi = __shfl((int)(u32)(v >> 32), src, 64);
  return ((u64)(u32)hi << 32) | (u32)lo;
}

// Torchvision BoxCoder.decode + clip, non-contracted fp32 to match reference.
__device__ __forceinline__ void decode_box(int row, int c,
    const float* __restrict__ reg, const float* __restrict__ props,
    float& x1, float& y1, float& x2, float& y2) {
  const float4 pr = *reinterpret_cast<const float4*>(props + (size_t)row * 4);
  float w = __fsub_rn(pr.z, pr.x), h = __fsub_rn(pr.w, pr.y);
  float cx = __fadd_rn(pr.x, 0.5f * w), cy = __fadd_rn(pr.y, 0.5f * h);
  const float4 rel = *reinterpret_cast<const float4*>(reg + ((size_t)row * Cc + c) * 4);
  float dx = __fdiv_rn(rel.x, 10.f), dy = __fdiv_rn(rel.y, 10.f);
  float dw = fminf(__fdiv_rn(rel.z, 5.f), BBOX_CLIP_F);
  float dh = fminf(__fdiv_rn(rel.w, 5.f), BBOX_CLIP_F);
  float pcx = __fadd_rn(__fmul_rn(dx, w), cx);
  float pcy = __fadd_rn(__fmul_rn(dy, h), cy);
  float pw = __fmul_rn(expf(dw), w);
  float ph = __fmul_rn(expf(dh), h);
  x1 = fminf(fmaxf(__fsub_rn(pcx, 0.5f * pw), 0.f), IMG_W);
  y1 = fminf(fmaxf(__fsub_rn(pcy, 0.5f * ph), 0.f), IMG_H);
  x2 = fminf(fmaxf(__fadd_rn(pcx, 0.5f * pw), 0.f), IMG_W);
  y2 = fminf(fmaxf(__fadd_rn(pcy, 0.5f * ph), 0.f), IMG_H);
}

// Batched drain (r9/r12-proven): 64 lanes decode+minsize-filter queued keys,
// compact survivors to the private segment, count into the LDS histogram.
__device__ __forceinline__ u32 drain(const u64* Qb, u32 n, int lane, int b,
    const float* __restrict__ reg, const float* __restrict__ props,
    u32* hist, u64* seg, u32 wout) {
  for (u32 qb = 0; qb < n; qb += 64) {
    const bool act = (qb + (u32)lane) < n;
    u64 key = act ? Qb[qb + lane] : 0ull;
    bool valid = false;
    u32 sb = 0;
    if (act) {
      sb = (u32)(key >> 32);
      const u32 idx = ~(u32)key;
      const int pn = (int)(idx / CM1);
      const int c = (int)(idx - (u32)pn * CM1) + 1;
      float x1, y1, x2, y2;
      decode_box(b * Np + pn, c, reg, props, x1, y1, x2, y2);
      valid = (__fsub_rn(x2, x1) >= MIN_SZ) && (__fsub_rn(y2, y1) >= MIN_SZ);
    }
    const u64 bal = __ballot(valid);
    if (valid) {
      seg[wout + (u32)__popcll(bal & ((1ull << lane) - 1ull))] = key;
      u32 bk = (sb - BUCK_BASE) >> BUCK_SHIFT;
      if (bk > (u32)(NBUCK - 1)) bk = NBUCK - 1;
      atomicAdd(&hist[bk], 1u);
    }
    wout += (u32)__popcll(bal);
  }
  return wout;
}

// Pass A (r12-verbatim): direct-register logits loads, 2 rounds of 16
// proposals per wave, prefix-scan emit, drain per round.
__global__ __launch_bounds__(256, 4) void passA_kernel(
    const float* __restrict__ logits, const float* __restrict__ reg,
    const float* __restrict__ props, u64* __restrict__ wseg,
    u32* __restrict__ wcnt, u32* __restrict__ ghist)
{
  __shared__ u64 qbuf[4][QCAP];                        // 10240 B
  __shared__ u32 hist[NBUCK];                          // 8192 B
  const int b = blockIdx.y;
  const int tid = threadIdx.x;
  const int wave = tid >> 6, lane = tid & 63;
  for (int i = tid; i < NBUCK; i += 256) hist[i] = 0;
  __syncthreads();

  const int wslot = (blockIdx.x << 2) + wave;
  u64* Q = qbuf[wave];
  u64* seg = wseg + (size_t)(b * WPI + wslot) * SEGCAP;
  u32 wout = 0;
  const int p = lane >> 2, qd = lane & 3;
  const int cnt_k = (qd == 3) ? 18 : 21;
  #pragma unroll
  for (int r = 0; r < 2; ++r) {
    const int n0 = wslot * CHUNK + r * 16;
    if (n0 >= Np) break;
    const int n_ = n0 + p;
    const float* lrow = logits + ((size_t)b * Np + n_) * Cc + qd * 21;
    float ev[21];
    #pragma unroll
    for (int k = 0; k < 21; ++k)
      ev[k] = (k < cnt_k) ? lrow[k] : -3.4e38f;
    float m = ev[0];
    #pragma unroll
    for (int k = 1; k < 21; ++k) m = fmaxf(m, ev[k]);
    m = fmaxf(m, __shfl_xor(m, 1, 64));
    m = fmaxf(m, __shfl_xor(m, 2, 64));
    float s = 0.f;
    #pragma unroll
    for (int k = 0; k < 21; ++k) {
      ev[k] = (k < cnt_k) ? expf(ev[k] - m) : 0.f;
      s += ev[k];
    }
    s += __shfl_xor(s, 1, 64);
    s += __shfl_xor(s, 2, 64);
    const float thr = SCORE_TH * s;
    // per-lane emit mask -> one wave prefix scan -> compacted queue writes
    u32 emask = 0;
    #pragma unroll
    for (int k = 0; k < 21; ++k) {
      const int c = qd * 21 + k;
      if (c > 0 && ev[k] > thr) emask |= (1u << k);
    }
    const u32 mycnt = __popc(emask);
    u32 inc = mycnt;
    #pragma unroll
    for (int o = 1; o < 64; o <<= 1) {
      const u32 v = (u32)__shfl_up((int)inc, o, 64);
      if (lane >= o) inc += v;
    }
    u32 pos = inc - mycnt;
    const u32 qtot = (u32)__shfl((int)inc, 63, 64);
    u32 em = emask;
    while (em) {
      const int k = (int)__builtin_ctz(em);
      em &= em - 1;
      const int c = qd * 21 + k;
      const u32 sb = __float_as_uint(__fdiv_rn(ev[k], s));
      const u32 idx = (u32)(n_ * CM1 + (c - 1));
      Q[pos++] = ((u64)sb << 32) | (u32)(~idx);
    }
    // drain the whole round (decode + minsize + hist + segment write)
    wout = drain(Q, qtot, lane, b, reg, props, hist, seg, wout);
  }
  if (lane == 0) wcnt[b * WPI + wslot] = wout;
  __syncthreads();
  for (int i = tid; i < NBUCK; i += 256) {
    const u32 v = hist[i];
    if (v) atomicAdd(&ghist[b * NBUCK + i], v);   // fire-and-forget
  }
}

// Per image: T = largest bucket with inclusive suffix >= KSEL (0 if total
// < KSEL); exclusive suffix offsets; total (clamped); also zeroes bfill.
__global__ void thresh_kernel(const u32* __restrict__ ghist, u32* __restrict__ gT,
                              u32* __restrict__ gTot, u32* __restrict__ boffs,
                              u32* __restrict__ bfill) {
  const int b = blockIdx.x;
  const int lane = threadIdx.x;  // 64 threads
  const u32* h = ghist + b * NBUCK;
  u32* bo = boffs + b * NBUCK;
  const int SEG = NBUCK / 64;
  u32 segsum = 0;
  for (int t = 0; t < SEG; ++t) segsum += h[lane * SEG + t];
  u32 suf = segsum;
  #pragma unroll
  for (int o = 1; o < 64; o <<= 1) {
    const u32 v = (u32)__shfl_down((int)suf, o, 64);
    if (lane + o < 64) suf += v;
  }
  u32 acc = suf - segsum;   // count in buckets strictly above this segment
  int myT = -1; u32 totv = 0;
  for (int t = SEG - 1; t >= 0; --t) {
    const int bk = lane * SEG + t;
    bo[bk] = acc;
    bfill[b * NBUCK + bk] = 0u;
    acc += h[bk];
    if (myT < 0 && acc >= (u32)KSEL) { myT = bk; totv = acc; }
  }
  int Tg = myT;
  #pragma unroll
  for (int o = 32; o; o >>= 1) Tg = max(Tg, __shfl_xor(Tg, o, 64));
  if (Tg < 0) {
    if (lane == 0) { gT[b] = 0u; gTot[b] = (acc < (u32)SELCAP) ? acc : (u32)SELCAP; }
  } else if (myT == Tg) {
    gT[b] = (u32)Tg;
    gTot[b] = (totv < (u32)SELCAP) ? totv : (u32)SELCAP;
  }
}

// Scatter (r12-verbatim): wave-per-segment, per-bucket fill atomics.
__global__ __launch_bounds__(256) void scatter_kernel(
    const u64* __restrict__ wseg, const u32* __restrict__ wcnt,
    const u32* __restrict__ gT, const u32* __restrict__ boffs,
    u32* __restrict__ bfill, u64* __restrict__ skeys)
{
  const int b = blockIdx.y;
  const u32 T = gT[b];
  const int wave = threadIdx.x >> 6, lane = threadIdx.x & 63;
  const u32 sgi = blockIdx.x * 4 + wave;
  if (sgi >= (u32)WPI) return;
  const u32 cnt = wcnt[b * WPI + sgi];
  const u64* seg = wseg + (size_t)(b * WPI + sgi) * SEGCAP;
  for (u32 i = lane; i < cnt; i += 64) {
    const u64 key = seg[i];
    const u32 sb = (u32)(key >> 32);
    u32 bk = (sb - BUCK_BASE) >> BUCK_SHIFT;
    if (bk > (u32)(NBUCK - 1)) bk = NBUCK - 1;
    if (bk >= T) {
      const u32 pos = boffs[b * NBUCK + bk] + atomicAdd(&bfill[b * NBUCK + bk], 1u);
      if (pos < (u32)SELCAP) skeys[(size_t)b * SELCAP + pos] = key;
    }
  }
}

// Runsort (r12-verbatim): wave-per-bucket register rank sort, src->dst.
__global__ __launch_bounds__(256) void runsort_kernel(
    const u64* __restrict__ skeys, u64* __restrict__ skeys2,
    const u32* __restrict__ gT, const u32* __restrict__ gTot,
    const u32* __restrict__ boffs, const u32* __restrict__ bfill)
{
  const int b = blockIdx.y;
  const int wave = threadIdx.x >> 6, lane = threadIdx.x & 63;
  const u32 bk = blockIdx.x * RS_WPB + wave;
  if (bk >= (u32)NBUCK || bk < gT[b]) return;
  const u32 total = gTot[b];
  const u32 start = boffs[b * NBUCK + bk];
  u32 L = bfill[b * NBUCK + bk];
  if (L == 0 || start >= (u32)KSEL || start >= total) return;
  if (start + L > total) L = total - start;
  const u64* run = skeys + (size_t)b * SELCAP + start;
  u64* dst = skeys2 + (size_t)b * SELCAP + start;
  if (L <= 128u) {
    const u64 k0 = (lane < (int)L) ? run[lane] : 0ull;
    const u64 k1 = (64 + lane < (int)L) ? run[64 + lane] : 0ull;
    u32 r0 = 0, r1 = 0;
    #pragma unroll
    for (int l = 0; l < 64; ++l) {
      const u64 o0 = shfl64(k0, l);
      const u64 o1 = shfl64(k1, l);
      r0 += (o0 > k0) + (o1 > k0);
      r1 += (o0 > k1) + (o1 > k1);
    }
    if (lane < (int)L) dst[r0] = k0;
    if (64 + lane < (int)L) dst[r1] = k1;
  } else {
    for (u32 i = lane; i < L; i += 64) {
      const u64 k = run[i];
      u32 r = 0;
      for (u32 q = 0; q < L; ++q) r += (run[q] > k);
      dst[r] = k;
    }
  }
}

// Tail (r12-verbatim): decode top-2048 to LDS SoA, greedy NMS (16-wave
// phase1 + wave-0 resolve), early-exit at 100, write outputs.
__global__ __launch_bounds__(1024) void tail_kernel(
    const u64* __restrict__ skeys2, const u32* __restrict__ gTot,
    const float* __restrict__ reg, const float* __restrict__ props,
    float* __restrict__ out)
{
  __shared__ u64 keys[KSEL];                                     // 16 KB
  __shared__ float obx1[KSEL], oby1[KSEL], obx2[KSEL], oby2[KSEL];
  __shared__ float oar[KSEL], osc[KSEL];                         // 48 KB
  __shared__ unsigned short keptIdx[NDET];
  __shared__ u32 supflags[64];
  __shared__ u32 sh_kc;
  const int b = blockIdx.x;
  const int tid = threadIdx.x;
  const int wave = tid >> 6, lane = tid & 63;
  const u32 total = gTot[b];
  if (tid == 0) sh_kc = 0;

  for (int i = tid; i < KSEL; i += 1024)
    keys[i] = (i < (int)total) ? skeys2[(size_t)b * SELCAP + i] : 0ull;
  __syncthreads();

  for (int t = tid; t < KSEL; t += 1024) {
    const u64 key = keys[t];
    float x1 = 0, y1 = 0, x2 = 0, y2 = 0, score = 0, lab = 0;
    if (key) {
      const u32 sb = (u32)(key >> 32);
      const u32 idx = ~(u32)key;
      const int n_ = (int)(idx / CM1);
      const int c = (int)(idx % CM1) + 1;
      score = __uint_as_float(sb);
      decode_box(b * Np + n_, c, reg, props, x1, y1, x2, y2);
      lab = (float)c;
    }
    const float offv = __fmul_rn(lab, LBLOFF);
    const float ox1 = __fadd_rn(x1, offv), oy1 = __fadd_rn(y1, offv);
    const float ox2 = __fadd_rn(x2, offv), oy2 = __fadd_rn(y2, offv);
    obx1[t] = ox1; oby1[t] = oy1; obx2[t] = ox2; oby2[t] = oy2;
    oar[t] = __fmul_rn(__fsub_rn(ox2, ox1), __fsub_rn(oy2, oy1));
    osc[t] = score;
  }
  __syncthreads();

  int kc = 0;
  for (int c = 0; c < 32 && kc < NDET; ++c) {
    if (tid < 64) supflags[tid] = 0;
    __syncthreads();
    const int j = (c << 6) + lane;
    const float cx1 = obx1[j], cy1 = oby1[j], cx2 = obx2[j], cy2 = oby2[j], ca = oar[j];
    bool sup = false;
    for (int k = wave; k < kc; k += 16) {
      const int ki = keptIdx[k];
      const float ltx = fmaxf(cx1, obx1[ki]), lty = fmaxf(cy1, oby1[ki]);
      const float rbx = fminf(cx2, obx2[ki]), rby = fminf(cy2, oby2[ki]);
      const float wx = fmaxf(__fsub_rn(rbx, ltx), 0.f);
      const float wy = fmaxf(__fsub_rn(rby, lty), 0.f);
      const float inter = __fmul_rn(wx, wy);
      const float denom = __fadd_rn(__fsub_rn(__fadd_rn(ca, oar[ki]), inter), 1e-9f);
      if (__fdiv_rn(inter, denom) > NMS_TH) sup = true;
    }
    if (sup) supflags[lane] = 1u;   // benign same-value race
    __syncthreads();
    if (wave == 0) {
      u64 rem = __ballot(supflags[lane] != 0u);
      u64 todo = __ballot(osc[j] > 0.f) & ~rem;
      int kcl = kc;
      while (todo && kcl < NDET) {
        const int jb = (int)__builtin_ctzll(todo);
        const int cj = (c << 6) + jb;
        if (lane == 0) keptIdx[kcl] = (unsigned short)cj;
        ++kcl;
        const float kx1 = obx1[cj], ky1 = oby1[cj], kx2 = obx2[cj], ky2 = oby2[cj], ka = oar[cj];
        const float ltx = fmaxf(kx1, cx1), lty = fmaxf(ky1, cy1);
        const float rbx = fminf(kx2, cx2), rby = fminf(ky2, cy2);
        const float wx = fmaxf(__fsub_rn(rbx, ltx), 0.f);
        const float wy = fmaxf(__fsub_rn(rby, lty), 0.f);
        const float inter = __fmul_rn(wx, wy);
        const float denom = __fadd_rn(__fsub_rn(__fadd_rn(ka, ca), inter), 1e-9f);
        const u64 w = __ballot(__fdiv_rn(inter, denom) > NMS_TH);
        rem |= w;
        todo &= ~rem;
        todo &= ~(1ull << jb);
      }
      if (lane == 0) sh_kc = (u32)kcl;
    }
    __syncthreads();
    kc = (int)sh_kc;
  }

  __syncthreads();
  const int kcl = (kc < NDET) ? kc : NDET;
  if (tid < NDET) {
    float bx1 = 0, by1 = 0, bx2 = 0, by2 = 0, sc = 0, lb = -1.f;
    if (tid < kcl) {
      const int i = keptIdx[tid];
      const u64 key = keys[i];
      const u32 idx = ~(u32)key;
      const int n_ = (int)(idx / CM1);
      const int cc = (int)(idx % CM1) + 1;
      decode_box(b * Np + n_, cc, reg, props, bx1, by1, bx2, by2);
      sc = osc[i];
      lb = (float)cc;
    }
    float* ob = out + (size_t)b * NDET * 4;
    ob[tid * 4 + 0] = bx1; ob[tid * 4 + 1] = by1;
    ob[tid * 4 + 2] = bx2; ob[tid * 4 + 3] = by2;
    out[Bn * NDET * 4 + b * NDET + tid] = sc;
    out[Bn * NDET * 4 + Bn * NDET + b * NDET + tid] = lb;
  }
}

extern "C" void kernel_launch(void* const* d_in, const int* in_sizes, int n_in,
                              void* d_out, int out_size, void* d_ws, size_t ws_size,
                              hipStream_t stream) {
  const float* logits = (const float*)d_in[0];
  const float* reg    = (const float*)d_in[1];
  const float* props  = (const float*)d_in[2];
  float* out = (float*)d_out;
  char* ws = (char*)d_ws;

  // Layout: [header | ghist]  <- memset 0 each call (16 KB)
  //         [bfill (zeroed by thresh) | boffs | skeys | skeys2 | wcnt | wseg]
  u32* gT   = (u32*)ws;                        // 2 u32
  u32* gTot = (u32*)(ws + 16);                 // 2 u32
  size_t off = 64;
  u32* ghist  = (u32*)(ws + off); off += (size_t)Bn * NBUCK * 4;   // 16 KB
  const size_t memset_bytes = off;
  u32* bfill  = (u32*)(ws + off); off += (size_t)Bn * NBUCK * 4;   // 16 KB
  u32* boffs  = (u32*)(ws + off); off += (size_t)Bn * NBUCK * 4;   // 16 KB
  u64* skeys  = (u64*)(ws + off); off += (size_t)Bn * SELCAP * 8;  // 64 KB
  u64* skeys2 = (u64*)(ws + off); off += (size_t)Bn * SELCAP * 8;  // 64 KB
  u32* wcnt   = (u32*)(ws + off); off += (size_t)Bn * WPI * 4;     // 13 KB
  off = (off + 255) & ~(size_t)255;
  u64* wseg   = (u64*)(ws + off); off += (size_t)Bn * WPI * SEGCAP * 8;  // 16 MB
  (void)ws_size;

  hipMemsetAsync(d_ws, 0, memset_bytes, stream);
  passA_kernel<<<dim3(BLKX, Bn), 256, 0, stream>>>(logits, reg, props, wseg, wcnt, ghist);
  thresh_kernel<<<dim3(Bn), 64, 0, stream>>>(ghist, gT, gTot, boffs, bfill);
  scatter_kernel<<<dim3((WPI + 3) / 4, Bn), 256, 0, stream>>>(wseg, wcnt, gT, boffs, bfill, skeys);
  runsort_kernel<<<dim3(NBUCK / RS_WPB, Bn), 256, 0, stream>>>(skeys, skeys2, gT, gTot, boffs, bfill);
  tail_kernel<<<dim3(Bn), 1024, 0, stream>>>(skeys2, gTot, reg, props, out);
}